// Round 12
// baseline (130.920 us; speedup 1.0000x reference)
//
#include <hip/hip_runtime.h>
#include <math.h>

// SinkhornM round 13 = R8 skeleton (47.2us best) with the TAIL PACKED f32x2
// across the row pair (v_pk_fma_f32 double-rate):
//  - MLP + prologue: verbatim R8 (proven, 56 VGPR, no spill).
//  - Tail state packed AFTER the scalar prologue: aaP[9], rmP[3], cmP[3],
//    tP[3] as {row0,row1} pairs -- same live bytes as R8's scalar arrays.
//  - Sinkhorn iteration fully packed (fma/mul), rcp stays scalar per lane
//    (no packed trans; trans proven hidden: R12 removed 32 trans/row -> 0 gain).
//  - Epilogue packed, unpacked only at the stores.
// Evidence for this lever: marginal VALU slots convert to time at ~60-70%
// across R0->R3 (-issue -> -dur), R12 (+issue -> +dur), R9 (+overhead -> +dur).
// Packed fma = 2 IEEE fmas -> bit-identical: absmax must stay 0.00390625.
// Tripwires: WRITE_SIZE ~69632 KB (spill); VGPR <= ~72.

#define QLOW  0.02f
#define QSPAN 0.96f
#define L2E   1.44269504088896f

constexpr int R = 2;

typedef __attribute__((ext_vector_type(2))) float f32x2;

__device__ __forceinline__ float frcp(float x) { return __builtin_amdgcn_rcpf(x); }
__device__ __forceinline__ f32x2 pfma(f32x2 a, f32x2 b, f32x2 c) {
    return __builtin_elementwise_fma(a, b, c);
}
__device__ __forceinline__ f32x2 prcp(f32x2 x) {
    f32x2 r; r.x = frcp(x.x); r.y = frcp(x.y); return r;
}

__global__ __launch_bounds__(256, 2) void sinkhorn_fused(
    const float* __restrict__ margins,
    const float* __restrict__ W1, const float* __restrict__ b1,
    const float* __restrict__ W2, const float* __restrict__ b2,
    const float* __restrict__ W3, const float* __restrict__ b3,
    float* __restrict__ out, int n)
{
    const int tid  = blockIdx.x * blockDim.x + threadIdx.x;
    const int lane = tid & 63;
    const int base = (tid >> 6) * (64 * R) + lane;  // rows base, base+64

    const float4* __restrict__ m4 = (const float4*)margins;

    float m[R][8];
#pragma unroll
    for (int r = 0; r < R; ++r) {
        const int row = base + 64 * r;
        const float4 a0 = m4[row * 2 + 0];
        const float4 a1 = m4[row * 2 + 1];
        m[r][0] = a0.x; m[r][1] = a0.y; m[r][2] = a0.z; m[r][3] = a0.w;
        m[r][4] = a1.x; m[r][5] = a1.y; m[r][6] = a1.z; m[r][7] = a1.w;
    }

    const f32x2* __restrict__ W1v = (const f32x2*)W1;  // (8,32) -> [k][16 pairs]
    const f32x2* __restrict__ W2v = (const f32x2*)W2;  // (32,16) -> [k][8 pairs]
    const f32x2* __restrict__ b1v = (const f32x2*)b1;
    const f32x2* __restrict__ b2v = (const f32x2*)b2;

    // ---- layer 1: h1 = relu(m @ W1 + b1), 32 wide = 16 pairs ----
    f32x2 h1[R][16];
#pragma unroll
    for (int j = 0; j < 16; ++j) {
        const f32x2 bb = b1v[j];
#pragma unroll
        for (int r = 0; r < R; ++r) h1[r][j] = bb;
    }
#pragma unroll
    for (int k = 0; k < 8; ++k) {
        f32x2 mk[R];
#pragma unroll
        for (int r = 0; r < R; ++r) { mk[r].x = m[r][k]; mk[r].y = m[r][k]; }
#pragma unroll
        for (int j = 0; j < 16; ++j) {
            const f32x2 w = W1v[k * 16 + j];
#pragma unroll
            for (int r = 0; r < R; ++r) h1[r][j] = pfma(mk[r], w, h1[r][j]);
        }
    }
    const f32x2 zero2 = {0.0f, 0.0f};
#pragma unroll
    for (int j = 0; j < 16; ++j)
#pragma unroll
        for (int r = 0; r < R; ++r)
            h1[r][j] = __builtin_elementwise_max(h1[r][j], zero2);

    // ---- layer 2: h2 = relu(h1 @ W2 + b2), 16 wide = 8 pairs ----
    f32x2 h2[R][8];
#pragma unroll
    for (int j = 0; j < 8; ++j) {
        const f32x2 bb = b2v[j];
#pragma unroll
        for (int r = 0; r < R; ++r) h2[r][j] = bb;
    }
#pragma unroll
    for (int k = 0; k < 32; ++k) {
        f32x2 hk[R];
#pragma unroll
        for (int r = 0; r < R; ++r) {
            const float s = (k & 1) ? h1[r][k >> 1].y : h1[r][k >> 1].x;
            hk[r].x = s; hk[r].y = s;
        }
#pragma unroll
        for (int j = 0; j < 8; ++j) {
            const f32x2 w = W2v[k * 8 + j];
#pragma unroll
            for (int r = 0; r < R; ++r) h2[r][j] = pfma(hk[r], w, h2[r][j]);
        }
    }
#pragma unroll
    for (int j = 0; j < 8; ++j)
#pragma unroll
        for (int r = 0; r < R; ++r)
            h2[r][j] = __builtin_elementwise_max(h2[r][j], zero2);

    // ---- layer 3: p = h2 @ W3 + b3, 9 wide = 4 pairs + 1 scalar ----
    f32x2 p01[R], p23[R], p45[R], p67[R];
    float p8[R];
    {
        const f32x2 b01 = {b3[0], b3[1]};
        const f32x2 b23 = {b3[2], b3[3]};
        const f32x2 b45 = {b3[4], b3[5]};
        const f32x2 b67 = {b3[6], b3[7]};
        const float b8  = b3[8];
#pragma unroll
        for (int r = 0; r < R; ++r) {
            p01[r] = b01; p23[r] = b23; p45[r] = b45; p67[r] = b67; p8[r] = b8;
        }
    }
#pragma unroll
    for (int k = 0; k < 16; ++k) {
        const f32x2 w01 = {W3[k * 9 + 0], W3[k * 9 + 1]};
        const f32x2 w23 = {W3[k * 9 + 2], W3[k * 9 + 3]};
        const f32x2 w45 = {W3[k * 9 + 4], W3[k * 9 + 5]};
        const f32x2 w67 = {W3[k * 9 + 6], W3[k * 9 + 7]};
        const float w8  = W3[k * 9 + 8];
#pragma unroll
        for (int r = 0; r < R; ++r) {
            const float s = (k & 1) ? h2[r][k >> 1].y : h2[r][k >> 1].x;
            f32x2 hb; hb.x = s; hb.y = s;
            p01[r] = pfma(hb, w01, p01[r]);
            p23[r] = pfma(hb, w23, p23[r]);
            p45[r] = pfma(hb, w45, p45[r]);
            p67[r] = pfma(hb, w67, p67[r]);
            p8[r]  = fmaf(s, w8, p8[r]);
        }
    }

    // ---- per-row scalar prologue (exp2-heavy, unchanged from R8) ----
    float aa[R][9];
    float rm[R][3], cm[R][3];
    float tt[R][3];
    float Vv[R];

#pragma unroll
    for (int r = 0; r < R; ++r) {
        const float l0 = p01[r].x * L2E, l1 = p01[r].y * L2E;
        const float l2 = p23[r].x * L2E, l3 = p23[r].y * L2E;

        const float a00 = exp2f(l0), a01 = exp2f(l1);
        const float a10 = exp2f(l2), a11 = exp2f(l3);
        const float h01 = (l0 + l1) * 0.5f, h23 = (l2 + l3) * 0.5f;
        const float a02 = exp2f(h01);
        const float a12 = exp2f(h23);
        const float a20 = exp2f((l0 + l2) * 0.5f);
        const float a21 = exp2f((l1 + l3) * 0.5f);
        const float a22 = exp2f((h01 + h23) * 0.5f);
        aa[r][0] = a00; aa[r][1] = a01; aa[r][2] = a02;
        aa[r][3] = a10; aa[r][4] = a11; aa[r][5] = a12;
        aa[r][6] = a20; aa[r][7] = a21; aa[r][8] = a22;

        const float s4 = fmaf(QSPAN, frcp(1.0f + exp2f(-L2E * p45[r].x)), QLOW);
        const float s5 = fmaf(QSPAN, frcp(1.0f + exp2f(-L2E * p45[r].y)), QLOW);
        const float s6 = fmaf(QSPAN, frcp(1.0f + exp2f(-L2E * p67[r].x)), QLOW);
        const float s7 = fmaf(QSPAN, frcp(1.0f + exp2f(-L2E * p67[r].y)), QLOW);

        rm[r][0] = m[r][0] * s4; rm[r][1] = m[r][1] * s5; rm[r][2] = m[r][2];
        cm[r][0] = m[r][3] * s6; cm[r][1] = m[r][4] * s7; cm[r][2] = m[r][5];

        tt[r][0] = (a00 + a01) + a02;   // A @ v with v = 1
        tt[r][1] = (a10 + a11) + a12;
        tt[r][2] = (a20 + a21) + a22;

        Vv[r] = exp2f(p8[r] * L2E);
    }

    // ---- pack tail state across the row pair (same live bytes) ----
    f32x2 aaP[9];
#pragma unroll
    for (int j = 0; j < 9; ++j) { aaP[j].x = aa[0][j]; aaP[j].y = aa[1][j]; }
    f32x2 rmP[3], cmP[3], tP[3];
#pragma unroll
    for (int j = 0; j < 3; ++j) {
        rmP[j].x = rm[0][j]; rmP[j].y = rm[1][j];
        cmP[j].x = cm[0][j]; cmP[j].y = cm[1][j];
        tP[j].x  = tt[0][j]; tP[j].y  = tt[1][j];
    }

    // ---- packed folded Sinkhorn (R8 math, v_pk_fma double-rate) ----
    f32x2 zp0, zp1, zp2, wp0, wp1, wp2;
#pragma unroll
    for (int it = 0; it < 10; ++it) {
        zp0 = rmP[0] * prcp(tP[0]);
        zp1 = rmP[1] * prcp(tP[1]);
        zp2 = rmP[2] * prcp(tP[2]);
        const f32x2 q0 = pfma(aaP[6], zp2, pfma(aaP[3], zp1, aaP[0] * zp0));
        const f32x2 q1 = pfma(aaP[7], zp2, pfma(aaP[4], zp1, aaP[1] * zp0));
        const f32x2 q2 = pfma(aaP[8], zp2, pfma(aaP[5], zp1, aaP[2] * zp0));
        wp0 = cmP[0] * prcp(q0);
        wp1 = cmP[1] * prcp(q1);
        wp2 = cmP[2] * prcp(q2);
        if (it < 9) {
            tP[0] = pfma(aaP[2], wp2, pfma(aaP[1], wp1, aaP[0] * wp0));
            tP[1] = pfma(aaP[5], wp2, pfma(aaP[4], wp1, aaP[3] * wp0));
            tP[2] = pfma(aaP[8], wp2, pfma(aaP[7], wp1, aaP[6] * wp0));
        }
    }

    // ---- packed epilogue: A_ij = u_i * a_ij * v_j ----
    const f32x2 A0 = zp0 * aaP[0] * wp0, A1 = zp0 * aaP[1] * wp1, A2 = zp0 * aaP[2] * wp2;
    const f32x2 A3 = zp1 * aaP[3] * wp0, A4 = zp1 * aaP[4] * wp1, A5 = zp1 * aaP[5] * wp2;
    const f32x2 A6 = zp2 * aaP[6] * wp0, A7 = zp2 * aaP[7] * wp1, A8 = zp2 * aaP[8] * wp2;

    const f32x2 m0P = {m[0][0], m[1][0]}, m1P = {m[0][1], m[1][1]};
    const f32x2 m3P = {m[0][3], m[1][3]}, m4P = {m[0][4], m[1][4]};
    const f32x2 um0 = m0P - rmP[0];
    const f32x2 um1 = m1P - rmP[1];
    const f32x2 uf0 = m3P - cmP[0];
    const f32x2 uf1 = m4P - cmP[1];

    float4* __restrict__ o4 = (float4*)out;
    float* __restrict__ oV = out + (size_t)n * 16;

    {
        const int row = base;
        o4[row * 4 + 0] = make_float4(A0.x, A1.x, A2.x, um0.x);
        o4[row * 4 + 1] = make_float4(A3.x, A4.x, A5.x, um1.x);
        o4[row * 4 + 2] = make_float4(A6.x, A7.x, A8.x, 0.0f);
        o4[row * 4 + 3] = make_float4(uf0.x, uf1.x, 0.0f, 0.0f);
        oV[row] = Vv[0];
    }
    {
        const int row = base + 64;
        o4[row * 4 + 0] = make_float4(A0.y, A1.y, A2.y, um0.y);
        o4[row * 4 + 1] = make_float4(A3.y, A4.y, A5.y, um1.y);
        o4[row * 4 + 2] = make_float4(A6.y, A7.y, A8.y, 0.0f);
        o4[row * 4 + 3] = make_float4(uf0.y, uf1.y, 0.0f, 0.0f);
        oV[row] = Vv[1];
    }
}

extern "C" void kernel_launch(void* const* d_in, const int* in_sizes, int n_in,
                              void* d_out, int out_size, void* d_ws, size_t ws_size,
                              hipStream_t stream) {
    const float* margins = (const float*)d_in[0];
    const float* W1 = (const float*)d_in[1];
    const float* b1 = (const float*)d_in[2];
    const float* W2 = (const float*)d_in[3];
    const float* b2 = (const float*)d_in[4];
    const float* W3 = (const float*)d_in[5];
    const float* b3 = (const float*)d_in[6];

    const int n = in_sizes[0] / 8;       // 1,048,576 rows
    const int threads = n / R;
    dim3 block(256), grid(threads / 256);

    sinkhorn_fused<<<grid, block, 0, stream>>>(margins, W1, b1, W2, b2, W3, b3,
                                               (float*)d_out, n);
}